// Round 13
// baseline (200.748 us; speedup 1.0000x reference)
//
#include <hip/hip_runtime.h>
#include <math.h>

typedef unsigned short u16;
typedef short v8s __attribute__((ext_vector_type(8)));
typedef float v4f __attribute__((ext_vector_type(4)));

#define AS1 __attribute__((address_space(1)))
#define AS3 __attribute__((address_space(3)))

__device__ __forceinline__ float bf2f(u16 u) {
    union { unsigned int i; float f; } c; c.i = ((unsigned int)u) << 16; return c.f;
}
__device__ __forceinline__ u16 f2bf(float f) {
    union { float f; unsigned int i; } c; c.f = f;
    unsigned int u = c.i;
    return (u16)((u + 0x7FFFu + ((u >> 16) & 1u)) >> 16);
}
// async global->LDS, 16B per lane. LDS dest = base + lane*16 (wave-uniform base).
__device__ __forceinline__ void gload_lds16(const void* g, void* l) {
    __builtin_amdgcn_global_load_lds((const AS1 void*)(uintptr_t)g,
                                     (AS3 void*)(unsigned int)(uintptr_t)l,
                                     16, 0, 0);
}

#define Nn 32
#define Tt 64
#define Vv 25
#define NP 51200        // N*T*V positions
#define NBLK 400        // M-tiles (51200/128); psum layout [256 d][400 m]

// ---------------------------------------------------------------------------
// prep (r3): bf16 weight transposes + bias2[w][d] + zero pad
// Wgb[d][k3*256+c]; Wtb[d][dt*256+c]
// ---------------------------------------------------------------------------
__global__ __launch_bounds__(256) void prep_kernel(
    const float* __restrict__ Wg, const float* __restrict__ Wt,
    const float* __restrict__ A, const float* __restrict__ bg,
    u16* __restrict__ Wgb, u16* __restrict__ Wtb,
    float* __restrict__ bias2, float* __restrict__ zpad)
{
    const int idx = blockIdx.x * 256 + threadIdx.x;
    const int stride = gridDim.x * 256;
    for (int i = idx; i < 256 * 2304; i += stride) {
        int d = i / 2304, r = i - d * 2304, dt = r >> 8, c = r & 255;
        Wtb[i] = f2bf(Wt[(d * 256 + c) * 9 + dt]);
    }
    for (int i = idx; i < 256 * 768; i += stride) {
        int d = i / 768, r = i - d * 768, k = r >> 8, c = r & 255;
        Wgb[i] = f2bf(Wg[(k * 256 + d) * 256 + c]);
    }
    for (int i = idx; i < 25 * 256; i += stride) {
        int w = i >> 8, d = i & 255;
        float s = 0.f;
        for (int k = 0; k < 3; ++k) {
            float cs = 0.f;
            for (int v = 0; v < 25; ++v) cs += A[(k * 25 + v) * 25 + w];
            s += bg[k * 256 + d] * cs;
        }
        bias2[i] = s;
    }
    for (int i = idx; i < 256; i += stride) zpad[i] = 0.f;
}

// ---------------------------------------------------------------------------
// xa2[p=(n,t,w)][k*256+c] = sum_v x[n,c,t,v] * A[k,v,w]   (bf16 out)
// ---------------------------------------------------------------------------
__global__ __launch_bounds__(256) void xa_kernel(
    const float* __restrict__ x, const float* __restrict__ A,
    u16* __restrict__ xa2)
{
    const int t = blockIdx.x, n = blockIdx.y;
    const int tid = threadIdx.x;              // = c
    __shared__ float xs[256 * 25];            // 25.6 KB

    for (int i = tid; i < 6400; i += 256) {
        int c = i / 25, v = i - c * 25;
        xs[i] = x[((n * 256 + c) * 64 + t) * 25 + v];
    }
    __syncthreads();

    float xr[25];
    #pragma unroll
    for (int v = 0; v < 25; ++v) xr[v] = xs[tid * 25 + v];

    const size_t pbase = ((size_t)n * 64 + t) * 25;
    #pragma unroll 1
    for (int k = 0; k < 3; ++k) {
        float o[25];
        #pragma unroll
        for (int w = 0; w < 25; ++w) {
            float acc = 0.f;
            #pragma unroll
            for (int v = 0; v < 25; ++v)
                acc = fmaf(xr[v], A[(k * 25 + v) * 25 + w], acc);
            o[w] = acc;
        }
        u16* dst = xa2 + k * 256 + tid;
        #pragma unroll
        for (int w = 0; w < 25; ++w)
            dst[(pbase + w) * 768] = f2bf(o[w]);
    }
}

// ---------------------------------------------------------------------------
// GEMM1 (r3 proven): 128x256 tile, BK=64, 512 threads = 8 waves (2M x 4N,
// per-wave 64x64). STAGE(A+B LDS) -> sync -> ds_read+MFMA -> sync. 48KB LDS.
// ---------------------------------------------------------------------------
__global__ __launch_bounds__(512) void gemm1_kernel(
    const u16* __restrict__ Ad, const u16* __restrict__ Bw,
    const float* __restrict__ bias, u16* __restrict__ outB)
{
    __shared__ u16 smem[24576];          // 48 KB
    u16* As = smem;                      // [128 rows][64 k] (swizzled)
    u16* Bs = smem + 8192;               // [256 rows][64 k] (swizzled)

    const int tid = threadIdx.x;
    const int wid = tid >> 6, lane = tid & 63;
    const int lr = lane & 15, hk = lane >> 4;
    const int wm = wid >> 2, wn = wid & 3;
    const int rA = lane >> 3, sA = lane & 7;

    const int orig = blockIdx.x;
    const int m = (orig & 7) * 50 + (orig >> 3);   // bijective XCD swizzle

    v4f acc[4][4];
    const v4f vzero = {0.f, 0.f, 0.f, 0.f};
    #pragma unroll
    for (int mf = 0; mf < 4; ++mf)
        #pragma unroll
        for (int nf = 0; nf < 4; ++nf) acc[mf][nf] = vzero;

    for (int kt = 0; kt < 12; ++kt) {
        #pragma unroll
        for (int i = 0; i < 2; ++i) {
            const int ch = wid + i * 8;
            const int row = ch * 8 + rA;
            const int ss = sA ^ rA;
            gload_lds16(Ad + (size_t)(m * 128 + row) * 768 + kt * 64 + ss * 8,
                        (char*)As + ch * 1024);
        }
        #pragma unroll
        for (int i = 0; i < 4; ++i) {
            const int ch = wid + i * 8;
            const int d = ch * 8 + rA;
            const int ss = sA ^ rA;
            gload_lds16(Bw + (size_t)d * 768 + kt * 64 + ss * 8,
                        (char*)Bs + ch * 1024);
        }
        __syncthreads();

        v8s a[4][2], b[4][2];
        #pragma unroll
        for (int mf = 0; mf < 4; ++mf)
            #pragma unroll
            for (int kk = 0; kk < 2; ++kk) {
                const int row = wm * 64 + mf * 16 + lr;
                const int slot = kk * 4 + hk;
                a[mf][kk] = *(const v8s*)((const char*)As + row * 128 + ((slot ^ (row & 7)) << 4));
            }
        #pragma unroll
        for (int nf = 0; nf < 4; ++nf)
            #pragma unroll
            for (int kk = 0; kk < 2; ++kk) {
                const int row = wn * 64 + nf * 16 + lr;
                const int slot = kk * 4 + hk;
                b[nf][kk] = *(const v8s*)((const char*)Bs + row * 128 + ((slot ^ (row & 7)) << 4));
            }
        #pragma unroll
        for (int kk = 0; kk < 2; ++kk)
            #pragma unroll
            for (int mf = 0; mf < 4; ++mf)
                #pragma unroll
                for (int nf = 0; nf < 4; ++nf)
                    acc[mf][nf] = __builtin_amdgcn_mfma_f32_16x16x32_bf16(
                        a[mf][kk], b[nf][kk], acc[mf][nf], 0, 0, 0);
        __syncthreads();
    }

    #pragma unroll
    for (int mf = 0; mf < 4; ++mf) {
        #pragma unroll
        for (int j = 0; j < 4; ++j) {
            const int p = m * 128 + wm * 64 + mf * 16 + hk * 4 + j;
            const int w = p % 25;
            #pragma unroll
            for (int nf = 0; nf < 4; ++nf) {
                const int d = wn * 64 + nf * 16 + lr;
                outB[(size_t)p * 256 + d] = f2bf(acc[mf][nf][j] + bias[w * 256 + d]);
            }
        }
    }
}

// ---------------------------------------------------------------------------
// TCN split-K: z_half[p][d] = (split==0 ? bt[d] : 0) +
//              sum_{kt in [split*18, +18)} y2T[p+(dt-4)*25][:] . Wtb[d][kt...]
// EXACT r3 2-barrier loop + geometry (128x256, 48KB LDS, 8 waves); the ONLY
// change vs r3 is the kt range and simplified epilogue. Grid 800 =
// 2 splits x 400 m -> 3.125 blocks/CU, saturating the 3-block LDS residency
// (r3's grid of 400 left it at 1.28 -- the measured util limiter).
// Deterministic: each half writes its own bf16 buffer; no atomics.
// ---------------------------------------------------------------------------
__global__ __launch_bounds__(512) void tcn_split_kernel(
    const u16* __restrict__ y2T, const u16* __restrict__ Wtb,
    const float* __restrict__ bt, u16* __restrict__ zb1,
    u16* __restrict__ zb2, const u16* __restrict__ zpad)
{
    __shared__ u16 smem[24576];          // 48 KB
    u16* As = smem;                      // [128 rows][64 k] (swizzled)
    u16* Bs = smem + 8192;               // [256 rows][64 k] (swizzled)

    const int tid = threadIdx.x;
    const int wid = tid >> 6, lane = tid & 63;
    const int lr = lane & 15, hk = lane >> 4;
    const int wm = wid >> 2, wn = wid & 3;
    const int rA = lane >> 3, sA = lane & 7;

    // bijective XCD swizzle over 800 blocks (800 % 8 == 0)
    const int orig = blockIdx.x;
    const int swz = (orig & 7) * 100 + (orig >> 3);
    const int split = swz / 400, m = swz % 400;
    const int kt0 = split * 18;
    u16* zbo = split ? zb2 : zb1;

    v4f acc[4][4];
    const v4f vzero = {0.f, 0.f, 0.f, 0.f};
    #pragma unroll
    for (int mf = 0; mf < 4; ++mf)
        #pragma unroll
        for (int nf = 0; nf < 4; ++nf) acc[mf][nf] = vzero;

    for (int kt = kt0; kt < kt0 + 18; ++kt) {
        // ---- stage A (16 chunks) + B (32 chunks); chunk = 8 rows x 128B ----
        #pragma unroll
        for (int i = 0; i < 2; ++i) {
            const int ch = wid + i * 8;
            const int row = ch * 8 + rA;
            const int ss = sA ^ rA;              // row&7 == rA
            const int dt = kt >> 2, c0 = (kt & 3) << 6;
            const int p = m * 128 + row;
            const int t = (p % 1600) / 25;
            const int tp = t + dt - 4;
            const u16* srcA = ((unsigned)tp < 64u)
                 ? (y2T + (size_t)(p + (dt - 4) * 25) * 256 + c0 + ss * 8)
                 : zpad;
            gload_lds16(srcA, (char*)As + ch * 1024);
        }
        #pragma unroll
        for (int i = 0; i < 4; ++i) {
            const int ch = wid + i * 8;
            const int d = ch * 8 + rA;
            const int ss = sA ^ rA;
            gload_lds16(Wtb + (size_t)d * 2304 + kt * 64 + ss * 8,
                        (char*)Bs + ch * 1024);
        }
        __syncthreads();   // staged data visible

        v8s a[4][2], b[4][2];
        #pragma unroll
        for (int mf = 0; mf < 4; ++mf)
            #pragma unroll
            for (int kk = 0; kk < 2; ++kk) {
                const int row = wm * 64 + mf * 16 + lr;
                const int slot = kk * 4 + hk;
                a[mf][kk] = *(const v8s*)((const char*)As + row * 128 + ((slot ^ (row & 7)) << 4));
            }
        #pragma unroll
        for (int nf = 0; nf < 4; ++nf)
            #pragma unroll
            for (int kk = 0; kk < 2; ++kk) {
                const int row = wn * 64 + nf * 16 + lr;
                const int slot = kk * 4 + hk;
                b[nf][kk] = *(const v8s*)((const char*)Bs + row * 128 + ((slot ^ (row & 7)) << 4));
            }
        #pragma unroll
        for (int kk = 0; kk < 2; ++kk)
            #pragma unroll
            for (int mf = 0; mf < 4; ++mf)
                #pragma unroll
                for (int nf = 0; nf < 4; ++nf)
                    acc[mf][nf] = __builtin_amdgcn_mfma_f32_16x16x32_bf16(
                        a[mf][kk], b[nf][kk], acc[mf][nf], 0, 0, 0);
        __syncthreads();   // protect LDS from next stage
    }

    // ---- epilogue: bias (split 0 only), bf16 partial z ----
    #pragma unroll
    for (int nf = 0; nf < 4; ++nf) {
        const int d = wn * 64 + nf * 16 + lr;
        const float bb = split ? 0.f : bt[d];
        #pragma unroll
        for (int mf = 0; mf < 4; ++mf) {
            #pragma unroll
            for (int j = 0; j < 4; ++j) {
                const int p = m * 128 + wm * 64 + mf * 16 + hk * 4 + j;
                zbo[(size_t)p * 256 + d] = f2bf(acc[mf][nf][j] + bb);
            }
        }
    }
}

// ---------------------------------------------------------------------------
// zsum: per-(m-tile, d) BN partials from z = zb1 + zb2  (L3-hot, coalesced)
// ---------------------------------------------------------------------------
__global__ __launch_bounds__(256) void zsum_kernel(
    const u16* __restrict__ zb1, const u16* __restrict__ zb2,
    float* __restrict__ psum, float* __restrict__ psq)
{
    const int m = blockIdx.x;      // 0..399
    const int d = threadIdx.x;     // 0..255
    const u16* r1 = zb1 + (size_t)m * 128 * 256 + d;
    const u16* r2 = zb2 + (size_t)m * 128 * 256 + d;
    float s = 0.f, q = 0.f;
    #pragma unroll 4
    for (int r = 0; r < 128; ++r) {
        const float z = bf2f(r1[r * 256]) + bf2f(r2[r * 256]);
        s += z; q += z * z;
    }
    psum[(size_t)d * NBLK + m] = s;
    psq[(size_t)d * NBLK + m]  = q;
}

// ---------------------------------------------------------------------------
// BN stats: reduce 400 m-tile partials per channel -> scale/shift
// ---------------------------------------------------------------------------
__global__ __launch_bounds__(256) void bn_stats_kernel(
    const float* __restrict__ psum, const float* __restrict__ psq,
    const float* __restrict__ gamma, const float* __restrict__ beta,
    float* __restrict__ scale, float* __restrict__ shift)
{
    const int d = blockIdx.x, tid = threadIdx.x;
    float s = 0.f, q = 0.f;
    for (int i = tid; i < NBLK; i += 256) {
        s += psum[(size_t)d * NBLK + i];
        q += psq[(size_t)d * NBLK + i];
    }
    #pragma unroll
    for (int off = 32; off; off >>= 1) {
        s += __shfl_down(s, off);
        q += __shfl_down(q, off);
    }
    __shared__ float rs[4], rq[4];
    if ((tid & 63) == 0) { rs[tid >> 6] = s; rq[tid >> 6] = q; }
    __syncthreads();
    if (tid == 0) {
        s = rs[0] + rs[1] + rs[2] + rs[3];
        q = rq[0] + rq[1] + rq[2] + rq[3];
        const float mean = s / 51200.f;
        const float var = q / 51200.f - mean * mean;
        const float inv = rsqrtf(var + 1e-5f);
        scale[d] = gamma[d] * inv;
        shift[d] = beta[d] - gamma[d] * inv * mean;
    }
}

// ---------------------------------------------------------------------------
// out[n,d,tv] = relu((zb1+zb2)*scale[d]+shift[d] + x[n,d,tv]); LDS transpose.
// ---------------------------------------------------------------------------
__global__ __launch_bounds__(256) void bn_apply_kernel(
    const u16* __restrict__ zb1, const u16* __restrict__ zb2,
    const float* __restrict__ x, const float* __restrict__ scale,
    const float* __restrict__ shift, float* __restrict__ out)
{
    const int chunk = blockIdx.x;   // 0..24
    const int n = blockIdx.y;       // 0..31
    const int tid = threadIdx.x;
    __shared__ float zs[128 * 66];  // 33.8 KB, padded rows
    const size_t p0 = (size_t)n * 1600 + chunk * 64;

    for (int half = 0; half < 2; ++half) {
        const int d0 = half * 128;
        if (half) __syncthreads();
        for (int i = tid; i < 128 * 64; i += 256) {
            const int pl = i >> 7, dl = i & 127;
            const size_t idx = (p0 + pl) * 256 + d0 + dl;
            zs[dl * 66 + pl] = bf2f(zb1[idx]) + bf2f(zb2[idx]);
        }
        __syncthreads();
        for (int i = tid; i < 128 * 64; i += 256) {
            const int dl = i >> 6, j = i & 63;
            const int d = d0 + dl;
            const size_t addr = ((size_t)n * 256 + d) * 1600 + chunk * 64 + j;
            const float r = zs[dl * 66 + j] * scale[d] + shift[d] + x[addr];
            out[addr] = fmaxf(r, 0.f);
        }
    }
}

extern "C" void kernel_launch(void* const* d_in, const int* in_sizes, int n_in,
                              void* d_out, int out_size, void* d_ws, size_t ws_size,
                              hipStream_t stream)
{
    const float* x     = (const float*)d_in[0];
    const float* A     = (const float*)d_in[1];
    const float* Wg    = (const float*)d_in[2];
    const float* bg    = (const float*)d_in[3];
    const float* Wt    = (const float*)d_in[4];
    const float* bt    = (const float*)d_in[5];
    const float* gamma = (const float*)d_in[6];
    const float* beta  = (const float*)d_in[7];
    float* out = (float*)d_out;

    char* w = (char*)d_ws;
    u16*   xa2   = (u16*)(w);                    // 78,643,200 B (dead after gemm1)
    u16*   zb1   = (u16*)(w);                    // 26,214,400 B -- aliases xa2
    u16*   y2T   = (u16*)(w + 78643200);         // 26,214,400 B
    u16*   zb2   = (u16*)(w + 104857600);        // 26,214,400 B
    u16*   Wgb   = (u16*)(w + 131072000);        //    393,216 B
    u16*   Wtb   = (u16*)(w + 131465216);        //  1,179,648 B
    float* bias2 = (float*)(w + 132644864);      //     25,600 B
    float* psum  = (float*)(w + 132670464);      //    409,600 B
    float* psq   = (float*)(w + 133080064);      //    409,600 B
    float* scale = (float*)(w + 133489664);      //      1,024 B
    float* shift = (float*)(w + 133490688);      //      1,024 B
    float* zpad  = (float*)(w + 133491712);      //      1,024 B (zeroed)

    prep_kernel<<<256, 256, 0, stream>>>(Wg, Wt, A, bg, Wgb, Wtb, bias2, zpad);
    xa_kernel<<<dim3(64, 32), 256, 0, stream>>>(x, A, xa2);
    gemm1_kernel<<<NBLK, 512, 0, stream>>>(xa2, Wgb, bias2, y2T);
    tcn_split_kernel<<<800, 512, 0, stream>>>(y2T, Wtb, bt, zb1, zb2,
                                              (const u16*)zpad);
    zsum_kernel<<<NBLK, 256, 0, stream>>>(zb1, zb2, psum, psq);
    bn_stats_kernel<<<256, 256, 0, stream>>>(psum, psq, gamma, beta, scale, shift);
    bn_apply_kernel<<<dim3(25, 32), 256, 0, stream>>>(zb1, zb2, x, scale, shift, out);
}

// Round 14
// 199.548 us; speedup vs baseline: 1.0060x; 1.0060x over previous
//
#include <hip/hip_runtime.h>
#include <math.h>

typedef unsigned short u16;
typedef short v8s __attribute__((ext_vector_type(8)));
typedef float v4f __attribute__((ext_vector_type(4)));

#define AS1 __attribute__((address_space(1)))
#define AS3 __attribute__((address_space(3)))

__device__ __forceinline__ float bf2f(u16 u) {
    union { unsigned int i; float f; } c; c.i = ((unsigned int)u) << 16; return c.f;
}
__device__ __forceinline__ u16 f2bf(float f) {
    union { float f; unsigned int i; } c; c.f = f;
    unsigned int u = c.i;
    return (u16)((u + 0x7FFFu + ((u >> 16) & 1u)) >> 16);
}
// async global->LDS, 16B per lane. LDS dest = base + lane*16 (wave-uniform base).
__device__ __forceinline__ void gload_lds16(const void* g, void* l) {
    __builtin_amdgcn_global_load_lds((const AS1 void*)(uintptr_t)g,
                                     (AS3 void*)(unsigned int)(uintptr_t)l,
                                     16, 0, 0);
}

#define Nn 32
#define Tt 64
#define Vv 25
#define NP 51200        // N*T*V positions
#define NBLK 400        // M-tiles (51200/128); psum layout [256 d][400 m]

// ---------------------------------------------------------------------------
// prep (r3): bf16 weight transposes + bias2[w][d] + zero pad
// Wgb[d][k3*256+c]; Wtb[d][dt*256+c]
// ---------------------------------------------------------------------------
__global__ __launch_bounds__(256) void prep_kernel(
    const float* __restrict__ Wg, const float* __restrict__ Wt,
    const float* __restrict__ A, const float* __restrict__ bg,
    u16* __restrict__ Wgb, u16* __restrict__ Wtb,
    float* __restrict__ bias2, float* __restrict__ zpad)
{
    const int idx = blockIdx.x * 256 + threadIdx.x;
    const int stride = gridDim.x * 256;
    for (int i = idx; i < 256 * 2304; i += stride) {
        int d = i / 2304, r = i - d * 2304, dt = r >> 8, c = r & 255;
        Wtb[i] = f2bf(Wt[(d * 256 + c) * 9 + dt]);
    }
    for (int i = idx; i < 256 * 768; i += stride) {
        int d = i / 768, r = i - d * 768, k = r >> 8, c = r & 255;
        Wgb[i] = f2bf(Wg[(k * 256 + d) * 256 + c]);
    }
    for (int i = idx; i < 25 * 256; i += stride) {
        int w = i >> 8, d = i & 255;
        float s = 0.f;
        for (int k = 0; k < 3; ++k) {
            float cs = 0.f;
            for (int v = 0; v < 25; ++v) cs += A[(k * 25 + v) * 25 + w];
            s += bg[k * 256 + d] * cs;
        }
        bias2[i] = s;
    }
    for (int i = idx; i < 256; i += stride) zpad[i] = 0.f;
}

// ---------------------------------------------------------------------------
// xa2[p=(n,t,w)][k*256+c] = sum_v x[n,c,t,v] * A[k,v,w]   (bf16 out)
// ---------------------------------------------------------------------------
__global__ __launch_bounds__(256) void xa_kernel(
    const float* __restrict__ x, const float* __restrict__ A,
    u16* __restrict__ xa2)
{
    const int t = blockIdx.x, n = blockIdx.y;
    const int tid = threadIdx.x;              // = c
    __shared__ float xs[256 * 25];            // 25.6 KB

    for (int i = tid; i < 6400; i += 256) {
        int c = i / 25, v = i - c * 25;
        xs[i] = x[((n * 256 + c) * 64 + t) * 25 + v];
    }
    __syncthreads();

    float xr[25];
    #pragma unroll
    for (int v = 0; v < 25; ++v) xr[v] = xs[tid * 25 + v];

    const size_t pbase = ((size_t)n * 64 + t) * 25;
    #pragma unroll 1
    for (int k = 0; k < 3; ++k) {
        float o[25];
        #pragma unroll
        for (int w = 0; w < 25; ++w) {
            float acc = 0.f;
            #pragma unroll
            for (int v = 0; v < 25; ++v)
                acc = fmaf(xr[v], A[(k * 25 + v) * 25 + w], acc);
            o[w] = acc;
        }
        u16* dst = xa2 + k * 256 + tid;
        #pragma unroll
        for (int w = 0; w < 25; ++w)
            dst[(pbase + w) * 768] = f2bf(o[w]);
    }
}

// ---------------------------------------------------------------------------
// GEMM1 (r3 proven): 128x256 tile, BK=64, 512 threads = 8 waves (2M x 4N,
// per-wave 64x64). STAGE(A+B LDS) -> sync -> ds_read+MFMA -> sync. 48KB LDS.
// ---------------------------------------------------------------------------
__global__ __launch_bounds__(512) void gemm1_kernel(
    const u16* __restrict__ Ad, const u16* __restrict__ Bw,
    const float* __restrict__ bias, u16* __restrict__ outB)
{
    __shared__ u16 smem[24576];          // 48 KB
    u16* As = smem;                      // [128 rows][64 k] (swizzled)
    u16* Bs = smem + 8192;               // [256 rows][64 k] (swizzled)

    const int tid = threadIdx.x;
    const int wid = tid >> 6, lane = tid & 63;
    const int lr = lane & 15, hk = lane >> 4;
    const int wm = wid >> 2, wn = wid & 3;
    const int rA = lane >> 3, sA = lane & 7;

    const int orig = blockIdx.x;
    const int m = (orig & 7) * 50 + (orig >> 3);   // bijective XCD swizzle

    v4f acc[4][4];
    const v4f vzero = {0.f, 0.f, 0.f, 0.f};
    #pragma unroll
    for (int mf = 0; mf < 4; ++mf)
        #pragma unroll
        for (int nf = 0; nf < 4; ++nf) acc[mf][nf] = vzero;

    for (int kt = 0; kt < 12; ++kt) {
        #pragma unroll
        for (int i = 0; i < 2; ++i) {
            const int ch = wid + i * 8;
            const int row = ch * 8 + rA;
            const int ss = sA ^ rA;
            gload_lds16(Ad + (size_t)(m * 128 + row) * 768 + kt * 64 + ss * 8,
                        (char*)As + ch * 1024);
        }
        #pragma unroll
        for (int i = 0; i < 4; ++i) {
            const int ch = wid + i * 8;
            const int d = ch * 8 + rA;
            const int ss = sA ^ rA;
            gload_lds16(Bw + (size_t)d * 768 + kt * 64 + ss * 8,
                        (char*)Bs + ch * 1024);
        }
        __syncthreads();

        v8s a[4][2], b[4][2];
        #pragma unroll
        for (int mf = 0; mf < 4; ++mf)
            #pragma unroll
            for (int kk = 0; kk < 2; ++kk) {
                const int row = wm * 64 + mf * 16 + lr;
                const int slot = kk * 4 + hk;
                a[mf][kk] = *(const v8s*)((const char*)As + row * 128 + ((slot ^ (row & 7)) << 4));
            }
        #pragma unroll
        for (int nf = 0; nf < 4; ++nf)
            #pragma unroll
            for (int kk = 0; kk < 2; ++kk) {
                const int row = wn * 64 + nf * 16 + lr;
                const int slot = kk * 4 + hk;
                b[nf][kk] = *(const v8s*)((const char*)Bs + row * 128 + ((slot ^ (row & 7)) << 4));
            }
        #pragma unroll
        for (int kk = 0; kk < 2; ++kk)
            #pragma unroll
            for (int mf = 0; mf < 4; ++mf)
                #pragma unroll
                for (int nf = 0; nf < 4; ++nf)
                    acc[mf][nf] = __builtin_amdgcn_mfma_f32_16x16x32_bf16(
                        a[mf][kk], b[nf][kk], acc[mf][nf], 0, 0, 0);
        __syncthreads();
    }

    #pragma unroll
    for (int mf = 0; mf < 4; ++mf) {
        #pragma unroll
        for (int j = 0; j < 4; ++j) {
            const int p = m * 128 + wm * 64 + mf * 16 + hk * 4 + j;
            const int w = p % 25;
            #pragma unroll
            for (int nf = 0; nf < 4; ++nf) {
                const int d = wn * 64 + nf * 16 + lr;
                outB[(size_t)p * 256 + d] = f2bf(acc[mf][nf][j] + bias[w * 256 + d]);
            }
        }
    }
}

// ---------------------------------------------------------------------------
// TCN, 4-WAVE blocks: 128x128 tile, BK=64, 256 threads = 4 waves (2M x 2N),
// per-wave 64x64 -- IDENTICAL per-wave register tile, ds_read pattern and
// 2-barrier schedule as r3; only the block is half-size. LDS 32KB ->
// residency cap 5 blocks/CU (vs r3's 8-wave blocks pinned at ~1.3).
// Grid 800 = 400 m x 2 N-halves; XCD swizzle gives each XCD one N-half
// (590KB Wtb slice L2-resident). A rows are t-shifted y2T reads (zero-pad
// at t edges). Epilogue: bf16 z + per-(d, m-tile) BN partials.
// ---------------------------------------------------------------------------
__global__ __launch_bounds__(256) void tcn_kernel(
    const u16* __restrict__ y2T, const u16* __restrict__ Wtb,
    const float* __restrict__ bt, u16* __restrict__ zb,
    float* __restrict__ psum, float* __restrict__ psq,
    const u16* __restrict__ zpad)
{
    __shared__ u16 smem[16384];          // 32 KB: A 16KB | B 16KB
    u16* As = smem;                      // [128 rows][64 k] (swizzled)
    u16* Bs = smem + 8192;               // [128 rows][64 k] (swizzled)

    const int tid = threadIdx.x;
    const int wid = tid >> 6, lane = tid & 63;   // wid 0..3
    const int lr = lane & 15, hk = lane >> 4;
    const int wm = wid >> 1, wn = wid & 1;       // 2M x 2N wave grid
    const int rA = lane >> 3, sA = lane & 7;

    // bijective XCD swizzle over 800 blocks: xcd 0-3 -> N-half 0, 4-7 -> half 1
    const int orig = blockIdx.x;
    const int swz = (orig & 7) * 100 + (orig >> 3);
    const int nh = swz / 400, m = swz % 400;
    const int d0 = nh * 128;

    v4f acc[4][4];
    const v4f vzero = {0.f, 0.f, 0.f, 0.f};
    #pragma unroll
    for (int mf = 0; mf < 4; ++mf)
        #pragma unroll
        for (int nf = 0; nf < 4; ++nf) acc[mf][nf] = vzero;

    for (int kt = 0; kt < 36; ++kt) {
        // ---- stage A 16 chunks + B 16 chunks (chunk = 8 rows x 128B);
        //      4 waves x 4 chunks each per matrix ----
        #pragma unroll
        for (int i = 0; i < 4; ++i) {
            const int ch = wid + i * 4;          // 0..15
            const int row = ch * 8 + rA;         // 0..127
            const int ss = sA ^ rA;              // row&7 == rA
            const int dt = kt >> 2, c0 = (kt & 3) << 6;
            const int p = m * 128 + row;
            const int t = (p % 1600) / 25;
            const int tp = t + dt - 4;
            const u16* srcA = ((unsigned)tp < 64u)
                 ? (y2T + (size_t)(p + (dt - 4) * 25) * 256 + c0 + ss * 8)
                 : zpad;
            gload_lds16(srcA, (char*)As + ch * 1024);
            gload_lds16(Wtb + (size_t)(d0 + row) * 2304 + kt * 64 + ss * 8,
                        (char*)Bs + ch * 1024);
        }
        __syncthreads();   // staged data visible

        v8s a[4][2], b[4][2];
        #pragma unroll
        for (int mf = 0; mf < 4; ++mf)
            #pragma unroll
            for (int kk = 0; kk < 2; ++kk) {
                const int row = wm * 64 + mf * 16 + lr;
                const int slot = kk * 4 + hk;
                a[mf][kk] = *(const v8s*)((const char*)As + row * 128 + ((slot ^ (row & 7)) << 4));
            }
        #pragma unroll
        for (int nf = 0; nf < 4; ++nf)
            #pragma unroll
            for (int kk = 0; kk < 2; ++kk) {
                const int row = wn * 64 + nf * 16 + lr;
                const int slot = kk * 4 + hk;
                b[nf][kk] = *(const v8s*)((const char*)Bs + row * 128 + ((slot ^ (row & 7)) << 4));
            }
        #pragma unroll
        for (int kk = 0; kk < 2; ++kk)
            #pragma unroll
            for (int mf = 0; mf < 4; ++mf)
                #pragma unroll
                for (int nf = 0; nf < 4; ++nf)
                    acc[mf][nf] = __builtin_amdgcn_mfma_f32_16x16x32_bf16(
                        a[mf][kk], b[nf][kk], acc[mf][nf], 0, 0, 0);
        __syncthreads();   // protect LDS from next stage
    }

    // ---- epilogue: bias, bf16 z, per-(d, m) BN partials ----
    float s[4], q[4];
    #pragma unroll
    for (int nf = 0; nf < 4; ++nf) {
        const int d = d0 + wn * 64 + nf * 16 + lr;
        const float bb = bt[d];
        s[nf] = 0.f; q[nf] = 0.f;
        #pragma unroll
        for (int mf = 0; mf < 4; ++mf) {
            #pragma unroll
            for (int j = 0; j < 4; ++j) {
                const int p = m * 128 + wm * 64 + mf * 16 + hk * 4 + j;
                const float zz = acc[mf][nf][j] + bb;
                zb[(size_t)p * 256 + d] = f2bf(zz);
                s[nf] += zz; q[nf] += zz * zz;
            }
        }
        s[nf] += __shfl_xor(s[nf], 16); s[nf] += __shfl_xor(s[nf], 32);
        q[nf] += __shfl_xor(q[nf], 16); q[nf] += __shfl_xor(q[nf], 32);
    }
    __syncthreads();
    float* red = (float*)smem;       // [2 wm][128 dl] s, then q (2KB)
    if (hk == 0) {
        #pragma unroll
        for (int nf = 0; nf < 4; ++nf) {
            const int dl = wn * 64 + nf * 16 + lr;
            red[wm * 128 + dl] = s[nf];
            red[256 + wm * 128 + dl] = q[nf];
        }
    }
    __syncthreads();
    if (tid < 128) {
        psum[(size_t)(d0 + tid) * NBLK + m] = red[tid] + red[128 + tid];
        psq[(size_t)(d0 + tid) * NBLK + m]  = red[256 + tid] + red[384 + tid];
    }
}

// ---------------------------------------------------------------------------
// BN stats: reduce 400 m-tile partials per channel -> scale/shift
// ---------------------------------------------------------------------------
__global__ __launch_bounds__(256) void bn_stats_kernel(
    const float* __restrict__ psum, const float* __restrict__ psq,
    const float* __restrict__ gamma, const float* __restrict__ beta,
    float* __restrict__ scale, float* __restrict__ shift)
{
    const int d = blockIdx.x, tid = threadIdx.x;
    float s = 0.f, q = 0.f;
    for (int i = tid; i < NBLK; i += 256) {
        s += psum[(size_t)d * NBLK + i];
        q += psq[(size_t)d * NBLK + i];
    }
    #pragma unroll
    for (int off = 32; off; off >>= 1) {
        s += __shfl_down(s, off);
        q += __shfl_down(q, off);
    }
    __shared__ float rs[4], rq[4];
    if ((tid & 63) == 0) { rs[tid >> 6] = s; rq[tid >> 6] = q; }
    __syncthreads();
    if (tid == 0) {
        s = rs[0] + rs[1] + rs[2] + rs[3];
        q = rq[0] + rq[1] + rq[2] + rq[3];
        const float mean = s / 51200.f;
        const float var = q / 51200.f - mean * mean;
        const float inv = rsqrtf(var + 1e-5f);
        scale[d] = gamma[d] * inv;
        shift[d] = beta[d] - gamma[d] * inv * mean;
    }
}

// ---------------------------------------------------------------------------
// out[n,d,tv] = relu(z[p][d]*scale[d]+shift[d] + x[n,d,tv]); LDS transpose.
// ---------------------------------------------------------------------------
__global__ __launch_bounds__(256) void bn_apply_kernel(
    const u16* __restrict__ zb, const float* __restrict__ x,
    const float* __restrict__ scale, const float* __restrict__ shift,
    float* __restrict__ out)
{
    const int chunk = blockIdx.x;   // 0..24
    const int n = blockIdx.y;       // 0..31
    const int tid = threadIdx.x;
    __shared__ u16 zs[128 * 66];    // 16.9 KB, padded rows
    const size_t p0 = (size_t)n * 1600 + chunk * 64;

    for (int half = 0; half < 2; ++half) {
        const int d0 = half * 128;
        if (half) __syncthreads();
        for (int i = tid; i < 128 * 64; i += 256) {
            const int pl = i >> 7, dl = i & 127;
            zs[dl * 66 + pl] = zb[(p0 + pl) * 256 + d0 + dl];
        }
        __syncthreads();
        for (int i = tid; i < 128 * 64; i += 256) {
            const int dl = i >> 6, j = i & 63;
            const int d = d0 + dl;
            const size_t addr = ((size_t)n * 256 + d) * 1600 + chunk * 64 + j;
            const float r = bf2f(zs[dl * 66 + j]) * scale[d] + shift[d] + x[addr];
            out[addr] = fmaxf(r, 0.f);
        }
    }
}

extern "C" void kernel_launch(void* const* d_in, const int* in_sizes, int n_in,
                              void* d_out, int out_size, void* d_ws, size_t ws_size,
                              hipStream_t stream)
{
    const float* x     = (const float*)d_in[0];
    const float* A     = (const float*)d_in[1];
    const float* Wg    = (const float*)d_in[2];
    const float* bg    = (const float*)d_in[3];
    const float* Wt    = (const float*)d_in[4];
    const float* bt    = (const float*)d_in[5];
    const float* gamma = (const float*)d_in[6];
    const float* beta  = (const float*)d_in[7];
    float* out = (float*)d_out;

    char* w = (char*)d_ws;
    u16*   xa2   = (u16*)(w);                    // 78,643,200 B
    u16*   y2T   = (u16*)(w + 78643200);         // 26,214,400 B
    u16*   zb    = (u16*)(w + 104857600);        // 26,214,400 B
    u16*   Wgb   = (u16*)(w + 131072000);        //    393,216 B
    u16*   Wtb   = (u16*)(w + 131465216);        //  1,179,648 B
    float* bias2 = (float*)(w + 132644864);      //     25,600 B
    float* psum  = (float*)(w + 132670464);      //    409,600 B
    float* psq   = (float*)(w + 133080064);      //    409,600 B
    float* scale = (float*)(w + 133489664);      //      1,024 B
    float* shift = (float*)(w + 133490688);      //      1,024 B
    float* zpad  = (float*)(w + 133491712);      //      1,024 B (zeroed)

    prep_kernel<<<256, 256, 0, stream>>>(Wg, Wt, A, bg, Wgb, Wtb, bias2, zpad);
    xa_kernel<<<dim3(64, 32), 256, 0, stream>>>(x, A, xa2);
    gemm1_kernel<<<NBLK, 512, 0, stream>>>(xa2, Wgb, bias2, y2T);
    tcn_kernel<<<800, 256, 0, stream>>>(y2T, Wtb, bt, zb, psum, psq,
                                        (const u16*)zpad);
    bn_stats_kernel<<<256, 256, 0, stream>>>(psum, psq, gamma, beta, scale, shift);
    bn_apply_kernel<<<dim3(25, 32), 256, 0, stream>>>(zb, x, scale, shift, out);
}